// Round 15
// baseline (222.509 us; speedup 1.0000x reference)
//
#include <hip/hip_runtime.h>
#include <hip/hip_bf16.h>
#include <stdint.h>

#define S_LEN 2048
#define NB    2
#define HQ    16
#define HKV   4
#define HD    128
#define KVB   64   // kv rows per staged tile
#define QBW   32   // q rows per wave
#define QBB   128  // q rows per block (4 waves)

typedef __bf16 bf16_t;
typedef __attribute__((ext_vector_type(8)))  __bf16 bf16x8;
typedef __attribute__((ext_vector_type(4)))  float  f32x4;
typedef __attribute__((ext_vector_type(16))) float  f32x16;
typedef __attribute__((ext_vector_type(4)))  unsigned int u32x4;

// heavy-first order of the 24 units per bh.
__constant__ int kOrder24[24] = {7,22,23,20,21, 6,18,19,16,17, 5,14,15,12,13,
                                 4,10,11,8,9, 3, 2, 1, 0};

__device__ __forceinline__ void gload_lds16(const bf16_t* g, bf16_t* l) {
  __builtin_amdgcn_global_load_lds(
      (const __attribute__((address_space(1))) unsigned int*)g,
      (__attribute__((address_space(3))) unsigned int*)l, 16, 0, 0);
}
__device__ __forceinline__ uint32_t pack2(float lo, float hi) {
  uint32_t a = (uint32_t)__builtin_bit_cast(unsigned short, (bf16_t)lo);
  uint32_t b = (uint32_t)__builtin_bit_cast(unsigned short, (bf16_t)hi);
  return a | (b << 16);
}

// ---------------- Q/K: L2-norm + RoPE (fast trig) + bf16 ----------------------
__global__ void qk_preproc_kernel(const float* __restrict__ xq,
                                  const float* __restrict__ xk,
                                  bf16_t* __restrict__ Qr,
                                  bf16_t* __restrict__ Kf) {
  int wid  = (blockIdx.x * blockDim.x + threadIdx.x) >> 6;
  int lane = threadIdx.x & 63;
  const int per_bs = HQ + HKV;
  int b   = wid / (S_LEN * per_bs);
  int rem = wid - b * (S_LEN * per_bs);
  int s   = rem / per_bs;
  int hh  = rem - s * per_bs;
  const float* src;
  float scale;
  if (hh < HQ) {
    src = xq + ((size_t)(b * S_LEN + s) * (HQ * HD)) + hh * HD;
    scale = 0.08838834764831845f * 1.4426950408889634f;  // (1/sqrt128)*log2e
  } else {
    src = xk + ((size_t)(b * S_LEN + s) * (HKV * HD)) + (hh - HQ) * HD;
    scale = 1.0f;
  }
  float x1 = src[lane];
  float x2 = src[64 + lane];
  float ss = x1 * x1 + x2 * x2;
  #pragma unroll
  for (int m = 1; m < 64; m <<= 1) ss += __shfl_xor(ss, m, 64);
  float rinv = scale / fmaxf(sqrtf(ss), 1e-6f);
  float inv = exp2f(-(float)lane * 0.20762050593046938f);
  float ang = (float)s * inv;
  float cs = __cosf(ang), sn = __sinf(ang);   // v_cos/v_sin fast path
  float q1 = x1 * rinv, q2 = x2 * rinv;
  bf16_t y1 = (bf16_t)(q1 * cs + q2 * sn);
  bf16_t y2 = (bf16_t)(q2 * cs - q1 * sn);
  if (hh < HQ) {
    bf16_t* dst = Qr + (((size_t)(b * HQ + hh) * S_LEN + s) * HD);
    dst[lane]      = y1;
    dst[64 + lane] = y2;
  } else {
    bf16_t* dst = Kf + ((size_t)((b * HKV + (hh - HQ)) * 32 + (s >> 6))) * (KVB * HD);
    const int sl = s & 63, half = sl >> 5, r0k = sl & 31;
    const int kk = lane >> 4, hi = (lane >> 3) & 1, pos = lane & 7;
    const int a1 = (kk * 128 + half * 64 + hi * 32 + r0k) * 8 + pos;
    dst[a1]        = y1;   // d = lane       (kk 0..3)
    dst[a1 + 4096] = y2;   // d = 64 + lane  (kk 4..7)
  }
}

// ---------------- V: coalesced read -> LDS transpose -> fragment-order write ---
__global__ void v_preproc_kernel(const float* __restrict__ xv,
                                 bf16_t* __restrict__ Vf) {
  __shared__ bf16_t tile[HD][34];    // [d][kv half], +2 pad kills write conflicts
  const int bid = blockIdx.x;
  const int bh  = bid >> 6;          // b*HKV + h
  const int r6  = bid & 63;
  const int sc  = r6 >> 1;           // 64-row s chunk (= tile t)
  const int j   = r6 & 1;            // which 32-kv half
  const int b = bh >> 2, hh = bh & 3;
  const int d  = threadIdx.x & 127;
  const int s2 = threadIdx.x >> 7;   // 0..1
  const float* src = xv + (size_t)b * S_LEN * (HKV * HD) + hh * HD;
  #pragma unroll 4
  for (int it = 0; it < 16; ++it) {
    int sl = it * 2 + s2;            // 0..31 (local)
    int s  = sc * 64 + j * 32 + sl;
    tile[d][sl] = (bf16_t)src[(size_t)s * (HKV * HD) + d];
  }
  __syncthreads();
  bf16_t* dstb = Vf + ((size_t)bh * 32 + sc) * (HD * KVB);
  const int dd   = threadIdx.x >> 1;           // d-row 0..127
  const int dt   = dd >> 5, r0v = dd & 31;
  #pragma unroll
  for (int i = 0; i < 2; ++i) {
    const int cl = (threadIdx.x & 1) * 2 + i;  // local chunk 0..3
    const int c  = j * 4 + cl;                 // global kv chunk (kk=c>>1, hi=c&1)
    const int n  = (c >> 1) * 256 + dt * 64 + (c & 1) * 32 + r0v;
    *reinterpret_cast<bf16x8*>(dstb + n * 8) =
        *reinterpret_cast<const bf16x8*>(&tile[dd][cl * 8]);
  }
}

// ---------------- Flash attention: 48KB LDS, panel-per-XCD, fused combine ------
// Per tile: bar1; issue V(t)+K(t+1); vmcnt(8); bar2; QK^T+softmax;
//           vmcnt(4); bar3; PV.   Counted waits keep prefetch in flight (T4).
// Partial (split) blocks: write partial, then the LAST finisher of each pair
// combines inline (device-fence + atomic flag; flags zeroed via memset).
__global__ __launch_bounds__(256, 3)
void attn_kernel(const bf16_t* __restrict__ Qr,
                 const bf16_t* __restrict__ Kf,
                 const bf16_t* __restrict__ Vf,
                 float* __restrict__ out,
                 float* __restrict__ Opart,
                 float2* __restrict__ mlpart,
                 int* __restrict__ flags,
                 int split, int upb) {
  __shared__ bf16_t Kb[2][KVB * HD];   // 16 KB x2, fragment order
  __shared__ bf16_t Vb[HD * KVB];      // 16 KB single buffer, fragment order
  __shared__ int sh_last;

  const int w    = threadIdx.x >> 6;
  const int lane = threadIdx.x & 63;
  const int r0   = lane & 31;
  const int hi   = lane >> 5;

  // decode flat id -> (panel, head, unit); panel pinned to XCD via lid&7
  const int lid = (int)blockIdx.x;
  const int p   = lid & 7;            // kv panel = b*4 + kvh
  const int qq  = lid >> 3;
  const int j   = qq & 3;             // head within panel
  const int k   = qq >> 2;            // unit index 0..upb-1
  const int b   = p >> 2;
  const int kvh = p & 3;
  const int h   = kvh * 4 + j;
  const int bh  = b * 16 + h;
  const int u   = split ? kOrder24[k] : (15 - k);
  int qt, t0, t1;
  if (!split || u < 8) {
    qt = u; t0 = 0; t1 = 2 * qt + 2;               // all kv tiles for this q-tile
  } else {
    int v = u - 8;
    qt = 8 + (v >> 1);
    int T = 2 * qt + 2, mid = qt + 1;              // two equal chunks of qt+1
    if (v & 1) { t0 = mid; t1 = T; } else { t0 = 0; t1 = mid; }
  }
  const bool full = (t0 == 0) && (t1 == 2 * qt + 2);
  const int qw0  = qt * QBB + w * QBW;
  const int qrow = qw0 + r0;
  const int qmax = qw0 + 31;

  const bf16_t* Qbase = Qr + (size_t)(b * HQ  + h  ) * S_LEN * HD;
  const bf16_t* Kbase = Kf + (size_t)(b * HKV + kvh) * 32 * (KVB * HD);
  const bf16_t* Vbase = Vf + (size_t)(b * HKV + kvh) * 32 * (HD * KVB);

  // linear staging offsets: wave w covers chunks [w*256, w*256+256)
  const int soff = (w * 256 + lane) * 8;           // + i*512 per iter

  // Q fragments (B-operand of swapped QK^T): lane holds Q[qrow][kk*16+hi*8 ..+8)
  bf16x8 qf[8];
  #pragma unroll
  for (int kk = 0; kk < 8; ++kk)
    qf[kk] = *reinterpret_cast<const bf16x8*>(Qbase + (size_t)qrow * HD + kk * 16 + hi * 8);

  f32x16 accO[4];
  #pragma unroll
  for (int dt = 0; dt < 4; ++dt)
    #pragma unroll
    for (int e = 0; e < 16; ++e) accO[dt][e] = 0.f;
  float m = -3.0e38f, l = 0.f;

  // prologue: stage K(t0) into Kb[0] (DMA, no VGPRs); no drain here
  {
    const bf16_t* kg = Kbase + (size_t)t0 * (KVB * HD);
    #pragma unroll
    for (int i = 0; i < 4; ++i)
      gload_lds16(kg + soff + i * 512, &Kb[0][soff + i * 512]);
  }

  for (int t = t0; t < t1; ++t) {
    const int pb = (t - t0) & 1;
    // bar1: all waves done reading Kb[pb^1] (tile t-1) and Vb (tile t-1's PV)
    __builtin_amdgcn_s_barrier();
    {
      const bf16_t* vg = Vbase + (size_t)t * (HD * KVB);
      #pragma unroll
      for (int i = 0; i < 4; ++i)                   // V(t) first (older)
        gload_lds16(vg + soff + i * 512, &Vb[soff + i * 512]);
      const int tn = (t + 1 < t1) ? t + 1 : t;      // last iter: dummy re-stage
      const bf16_t* kg = Kbase + (size_t)tn * (KVB * HD);
      #pragma unroll
      for (int i = 0; i < 4; ++i)                   // then K(t+1)
        gload_lds16(kg + soff + i * 512, &Kb[pb ^ 1][soff + i * 512]);
    }
    // wait K(t) (the 8 newer = V(t)+K(t+1) stay in flight)
    asm volatile("s_waitcnt vmcnt(8)" ::: "memory");
    __builtin_amdgcn_sched_barrier(0);
    __builtin_amdgcn_s_barrier();      // bar2: tile-t K visible block-wide
    __builtin_amdgcn_sched_barrier(0);

    const int kv0 = t * KVB;
    const bool active = (kv0 <= qmax);
    float p2[32];
    u32x4 pw[4];
    if (active) {
      // ---- S^T = K Q^T : fragment reads are base + kk*1024(+512) + lane*8
      const bf16_t* kb = &Kb[pb][0];
      f32x16 st0, st1;
      #pragma unroll
      for (int e = 0; e < 16; ++e) { st0[e] = 0.f; st1[e] = 0.f; }
      __builtin_amdgcn_s_setprio(1);
      #pragma unroll
      for (int kk = 0; kk < 8; ++kk) {
        bf16x8 k0 = *reinterpret_cast<const bf16x8*>(kb + kk * 1024 + lane * 8);
        bf16x8 k1 = *reinterpret_cast<const bf16x8*>(kb + kk * 1024 + 512 + lane * 8);
        st0 = __builtin_amdgcn_mfma_f32_32x32x16_bf16(k0, qf[kk], st0, 0, 0, 0);
        st1 = __builtin_amdgcn_mfma_f32_32x32x16_bf16(k1, qf[kk], st1, 0, 0, 0);
      }
      __builtin_amdgcn_s_setprio(0);

      // ---- in-register softmax (lane owns q-row r0; partner lane other 16)
      const bool need_mask = (kv0 + 63 > qw0);
      #pragma unroll
      for (int jj = 0; jj < 2; ++jj)
        #pragma unroll
        for (int e = 0; e < 16; ++e) {
          float s = jj ? st1[e] : st0[e];
          if (need_mask) {
            int kv = kv0 + jj * 32 + (e & 3) + 8 * (e >> 2) + 4 * hi;
            s = (kv > qrow) ? -3.0e38f : s;
          }
          p2[jj * 16 + e] = s;
        }
      float mt[16];
      #pragma unroll
      for (int e = 0; e < 16; ++e) mt[e] = fmaxf(p2[e], p2[e + 16]);
      #pragma unroll
      for (int e = 0; e < 8; ++e) mt[e] = fmaxf(mt[e], mt[e + 8]);
      #pragma unroll
      for (int e = 0; e < 4; ++e) mt[e] = fmaxf(mt[e], mt[e + 4]);
      float lmx = fmaxf(fmaxf(mt[0], mt[1]), fmaxf(mt[2], mt[3]));
      float cmx = fmaxf(lmx, __shfl_xor(lmx, 32, 64));
      if (!__all(cmx <= m + 8.0f)) {        // T13 defer-max
        float mnew = fmaxf(m, cmx);
        float resc = __builtin_amdgcn_exp2f(m - mnew);
        m = mnew;
        l *= resc;
        #pragma unroll
        for (int dt = 0; dt < 4; ++dt)
          #pragma unroll
          for (int e = 0; e < 16; ++e) accO[dt][e] *= resc;
      }
      #pragma unroll
      for (int e = 0; e < 32; ++e) p2[e] = __builtin_amdgcn_exp2f(p2[e] - m);
      float sv[16];
      #pragma unroll
      for (int e = 0; e < 16; ++e) sv[e] = p2[e] + p2[e + 16];
      #pragma unroll
      for (int e = 0; e < 8; ++e) sv[e] += sv[e + 8];
      #pragma unroll
      for (int e = 0; e < 4; ++e) sv[e] += sv[e + 4];
      float lsum = (sv[0] + sv[1]) + (sv[2] + sv[3]);
      l += lsum + __shfl_xor(lsum, 32, 64);

      // ---- P -> bf16 B-fragments (partner exchange via shfl_xor)
      #pragma unroll
      for (int jj = 0; jj < 2; ++jj) {
        const int o = jj * 16;
        {
          uint32_t A = pack2(p2[o + 0], p2[o + 1]);
          uint32_t C = pack2(p2[o + 2], p2[o + 3]);
          uint32_t B = pack2(p2[o + 4], p2[o + 5]);
          uint32_t D = pack2(p2[o + 6], p2[o + 7]);
          uint32_t At = __shfl_xor(A, 32, 64), Ct = __shfl_xor(C, 32, 64);
          uint32_t Bt = __shfl_xor(B, 32, 64), Dt = __shfl_xor(D, 32, 64);
          pw[2 * jj] = hi ? (u32x4){Bt, Dt, B, D} : (u32x4){A, C, At, Ct};
        }
        {
          uint32_t A = pack2(p2[o + 8],  p2[o + 9]);
          uint32_t C = pack2(p2[o + 10], p2[o + 11]);
          uint32_t B = pack2(p2[o + 12], p2[o + 13]);
          uint32_t D = pack2(p2[o + 14], p2[o + 15]);
          uint32_t At = __shfl_xor(A, 32, 64), Ct = __shfl_xor(C, 32, 64);
          uint32_t Bt = __shfl_xor(B, 32, 64), Dt = __shfl_xor(D, 32, 64);
          pw[2 * jj + 1] = hi ? (u32x4){Bt, Dt, B, D} : (u32x4){A, C, At, Ct};
        }
      }
    }

    // wait V(t) (K(t+1) stays in flight), then block-wide visibility
    asm volatile("s_waitcnt vmcnt(4)" ::: "memory");
    __builtin_amdgcn_sched_barrier(0);
    __builtin_amdgcn_s_barrier();      // bar3: tile-t V visible block-wide
    __builtin_amdgcn_sched_barrier(0);

    if (active) {
      // ---- O^T += V^T P^T : fragment reads base + kk*2048 + dt*512 + lane*8
      const bf16_t* vb = &Vb[0];
      __builtin_amdgcn_s_setprio(1);
      #pragma unroll
      for (int kk = 0; kk < 4; ++kk) {
        bf16x8 pf = __builtin_bit_cast(bf16x8, pw[kk]);
        #pragma unroll
        for (int dt = 0; dt < 4; ++dt) {
          bf16x8 vf = *reinterpret_cast<const bf16x8*>(vb + kk * 2048 + dt * 512 + lane * 8);
          accO[dt] = __builtin_amdgcn_mfma_f32_32x32x16_bf16(vf, pf, accO[dt], 0, 0, 0);
        }
      }
      __builtin_amdgcn_s_setprio(0);
    }
  }

  if (full) {
    // ---- direct output
    const float inv = 1.0f / l;
    float* orow = out + ((size_t)(b * S_LEN + qrow) * (HQ * HD)) + h * HD + hi * 4;
    #pragma unroll
    for (int dt = 0; dt < 4; ++dt)
      #pragma unroll
      for (int rg = 0; rg < 4; ++rg) {
        f32x4 v4 = { accO[dt][4 * rg + 0] * inv, accO[dt][4 * rg + 1] * inv,
                     accO[dt][4 * rg + 2] * inv, accO[dt][4 * rg + 3] * inv };
        *reinterpret_cast<f32x4*>(orow + dt * 32 + rg * 8) = v4;
      }
  } else {
    // ---- partial output (unnormalized, with local m,l)
    const int c    = (t0 != 0) ? 1 : 0;
    const int j2   = (bh << 3) + (qt - 8);       // pair index 0..255
    const int pidx = j2 * 2 + c;
    float* Op = Opart + (size_t)pidx * (QBB * HD) + (size_t)(w * QBW + r0) * HD + hi * 4;
    #pragma unroll
    for (int dt = 0; dt < 4; ++dt)
      #pragma unroll
      for (int rg = 0; rg < 4; ++rg) {
        f32x4 v4 = { accO[dt][4 * rg + 0], accO[dt][4 * rg + 1],
                     accO[dt][4 * rg + 2], accO[dt][4 * rg + 3] };
        *reinterpret_cast<f32x4*>(Op + dt * 32 + rg * 8) = v4;
      }
    if (!hi) mlpart[(size_t)pidx * QBB + w * QBW + r0] = make_float2(m, l);

    // ---- fused combine: the LAST-finishing chunk block of the pair combines
    __threadfence();                   // each thread: own stores device-visible
    __syncthreads();                   // all threads' stores issued+fenced
    if (threadIdx.x == 0)
      sh_last = (atomicAdd(&flags[j2], 1) == 1) ? 1 : 0;
    __syncthreads();
    if (sh_last) {
      __threadfence();                 // acquire side
      const int rr = threadIdx.x >> 1;            // 0..127
      const int d0 = (threadIdx.x & 1) * 64;
      const size_t pj0 = (size_t)(j2 * 2)     * (QBB * HD) + (size_t)rr * HD + d0;
      const size_t pj1 = (size_t)(j2 * 2 + 1) * (QBB * HD) + (size_t)rr * HD + d0;
      const float2 ml0 = mlpart[(size_t)(j2 * 2)     * QBB + rr];
      const float2 ml1 = mlpart[(size_t)(j2 * 2 + 1) * QBB + rr];
      const float M  = fmaxf(ml0.x, ml1.x);
      float a0 = exp2f(ml0.x - M), a1 = exp2f(ml1.x - M);
      const float invl = 1.0f / (a0 * ml0.y + a1 * ml1.y);
      a0 *= invl; a1 *= invl;
      const int qr2 = qt * QBB + rr;
      float* orow = out + ((size_t)(b * S_LEN + qr2) * (HQ * HD)) + h * HD + d0;
      #pragma unroll
      for (int i = 0; i < 16; ++i) {
        f32x4 o0 = *reinterpret_cast<const f32x4*>(Opart + pj0 + i * 4);
        f32x4 o1 = *reinterpret_cast<const f32x4*>(Opart + pj1 + i * 4);
        f32x4 res = { a0 * o0[0] + a1 * o1[0], a0 * o0[1] + a1 * o1[1],
                      a0 * o0[2] + a1 * o1[2], a0 * o0[3] + a1 * o1[3] };
        *reinterpret_cast<f32x4*>(orow + i * 4) = res;
      }
    }
  }
}

extern "C" void kernel_launch(void* const* d_in, const int* in_sizes, int n_in,
                              void* d_out, int out_size, void* d_ws, size_t ws_size,
                              hipStream_t stream) {
  const float* xq = (const float*)d_in[0];
  const float* xk = (const float*)d_in[1];
  const float* xv = (const float*)d_in[2];
  float* out = (float*)d_out;

  char* ws = (char*)d_ws;
  size_t off = 0;
  bf16_t* Qr = (bf16_t*)(ws + off); off += (size_t)NB * HQ  * S_LEN * HD * sizeof(bf16_t);
  bf16_t* Kf = (bf16_t*)(ws + off); off += (size_t)NB * HKV * S_LEN * HD * sizeof(bf16_t);
  bf16_t* Vf = (bf16_t*)(ws + off); off += (size_t)NB * HKV * S_LEN * HD * sizeof(bf16_t);
  float*  Opart  = (float*)(ws + off);  off += (size_t)512 * QBB * HD * sizeof(float);
  float2* mlpart = (float2*)(ws + off); off += (size_t)512 * QBB * sizeof(float2);
  int*    flags  = (int*)(ws + off);    off += 256 * sizeof(int);
  const int split = (ws_size >= off) ? 1 : 0;   // split-K needs the partial buffers
  const int upb   = split ? 24 : 16;            // units per (b,h)

  if (split)
    hipMemsetAsync(flags, 0, 256 * sizeof(int), stream);

  const int nrow = NB * S_LEN * (HQ + HKV);
  qk_preproc_kernel<<<nrow / 4, 256, 0, stream>>>(xq, xk, Qr, Kf);

  v_preproc_kernel<<<NB * HKV * 64, 256, 0, stream>>>(xv, Vf);

  attn_kernel<<<32 * upb, 256, 0, stream>>>(Qr, Kf, Vf, out, Opart, mlpart,
                                            flags, split, upb);
}

// Round 16
// 94.447 us; speedup vs baseline: 2.3559x; 2.3559x over previous
//
#include <hip/hip_runtime.h>
#include <hip/hip_bf16.h>
#include <stdint.h>

#define S_LEN 2048
#define NB    2
#define HQ    16
#define HKV   4
#define HD    128
#define KVB   64   // kv rows per staged tile
#define QBW   32   // q rows per wave
#define QBB   128  // q rows per block (4 waves)

typedef __bf16 bf16_t;
typedef __attribute__((ext_vector_type(8)))  __bf16 bf16x8;
typedef __attribute__((ext_vector_type(4)))  float  f32x4;
typedef __attribute__((ext_vector_type(16))) float  f32x16;
typedef __attribute__((ext_vector_type(4)))  unsigned int u32x4;

#define NVBLK 512          // v-preproc blocks (placed first in merged grid)

// heavy-first order of the 24 units per bh.
__constant__ int kOrder24[24] = {7,22,23,20,21, 6,18,19,16,17, 5,14,15,12,13,
                                 4,10,11,8,9, 3, 2, 1, 0};

__device__ __forceinline__ void gload_lds16(const bf16_t* g, bf16_t* l) {
  __builtin_amdgcn_global_load_lds(
      (const __attribute__((address_space(1))) unsigned int*)g,
      (__attribute__((address_space(3))) unsigned int*)l, 16, 0, 0);
}
__device__ __forceinline__ uint32_t pack2(float lo, float hi) {
  uint32_t a = (uint32_t)__builtin_bit_cast(unsigned short, (bf16_t)lo);
  uint32_t b = (uint32_t)__builtin_bit_cast(unsigned short, (bf16_t)hi);
  return a | (b << 16);
}

// ---------------- merged preproc: v-transpose blocks first, then q/k blocks ----
// Q: row-major [b][h][s][d], scale*log2e folded in.
// K: FRAGMENT-ORDER panels Kf[b][kvh][t][chunk n][8], n = kk*128+half*64+hi*32+r0
// Vf[b][kvh][t][chunk n][8], n = kk*256+dt*64+hi*32+r0 (V^T rows).
__global__ void preproc_kernel(const float* __restrict__ xq,
                               const float* __restrict__ xk,
                               const float* __restrict__ xv,
                               bf16_t* __restrict__ Qr,
                               bf16_t* __restrict__ Kf,
                               bf16_t* __restrict__ Vf) {
  __shared__ bf16_t tile[HD][34];    // v-path only; +2 pad kills write conflicts
  if (blockIdx.x < NVBLK) {
    // ---------- V path: coalesced read -> LDS transpose -> fragment-order write
    const int bid = blockIdx.x;
    const int bh  = bid >> 6;          // b*HKV + h
    const int r6  = bid & 63;
    const int sc  = r6 >> 1;           // 64-row s chunk (= tile t)
    const int j   = r6 & 1;            // which 32-kv half
    const int b = bh >> 2, hh = bh & 3;
    const int d  = threadIdx.x & 127;
    const int s2 = threadIdx.x >> 7;   // 0..1
    const float* src = xv + (size_t)b * S_LEN * (HKV * HD) + hh * HD;
    #pragma unroll 4
    for (int it = 0; it < 16; ++it) {
      int sl = it * 2 + s2;            // 0..31 (local)
      int s  = sc * 64 + j * 32 + sl;
      tile[d][sl] = (bf16_t)src[(size_t)s * (HKV * HD) + d];
    }
    __syncthreads();
    bf16_t* dstb = Vf + ((size_t)bh * 32 + sc) * (HD * KVB);
    const int dd   = threadIdx.x >> 1;           // d-row 0..127
    const int dt   = dd >> 5, r0v = dd & 31;
    #pragma unroll
    for (int i = 0; i < 2; ++i) {
      const int cl = (threadIdx.x & 1) * 2 + i;  // local chunk 0..3
      const int c  = j * 4 + cl;                 // global kv chunk
      const int n  = (c >> 1) * 256 + dt * 64 + (c & 1) * 32 + r0v;
      *reinterpret_cast<bf16x8*>(dstb + n * 8) =
          *reinterpret_cast<const bf16x8*>(&tile[dd][cl * 8]);
    }
    return;
  }
  // ---------- Q/K path: L2-norm + RoPE (fast trig) + bf16
  int wid  = ((blockIdx.x - NVBLK) * blockDim.x + threadIdx.x) >> 6;
  int lane = threadIdx.x & 63;
  const int per_bs = HQ + HKV;
  int b   = wid / (S_LEN * per_bs);
  int rem = wid - b * (S_LEN * per_bs);
  int s   = rem / per_bs;
  int hh  = rem - s * per_bs;
  const float* src;
  float scale;
  if (hh < HQ) {
    src = xq + ((size_t)(b * S_LEN + s) * (HQ * HD)) + hh * HD;
    scale = 0.08838834764831845f * 1.4426950408889634f;  // (1/sqrt128)*log2e
  } else {
    src = xk + ((size_t)(b * S_LEN + s) * (HKV * HD)) + (hh - HQ) * HD;
    scale = 1.0f;
  }
  float x1 = src[lane];
  float x2 = src[64 + lane];
  float ss = x1 * x1 + x2 * x2;
  #pragma unroll
  for (int mm = 1; mm < 64; mm <<= 1) ss += __shfl_xor(ss, mm, 64);
  float rinv = scale / fmaxf(sqrtf(ss), 1e-6f);
  float inv = exp2f(-(float)lane * 0.20762050593046938f);
  float ang = (float)s * inv;
  float cs = __cosf(ang), sn = __sinf(ang);   // v_cos/v_sin fast path
  float q1 = x1 * rinv, q2 = x2 * rinv;
  bf16_t y1 = (bf16_t)(q1 * cs + q2 * sn);
  bf16_t y2 = (bf16_t)(q2 * cs - q1 * sn);
  if (hh < HQ) {
    bf16_t* dst = Qr + (((size_t)(b * HQ + hh) * S_LEN + s) * HD);
    dst[lane]      = y1;
    dst[64 + lane] = y2;
  } else {
    bf16_t* dst = Kf + ((size_t)((b * HKV + (hh - HQ)) * 32 + (s >> 6))) * (KVB * HD);
    const int sl = s & 63, half = sl >> 5, r0k = sl & 31;
    const int kk = lane >> 4, hi = (lane >> 3) & 1, pos = lane & 7;
    const int a1 = (kk * 128 + half * 64 + hi * 32 + r0k) * 8 + pos;
    dst[a1]        = y1;   // d = lane       (kk 0..3)
    dst[a1 + 4096] = y2;   // d = 64 + lane  (kk 4..7)
  }
}

// ---------------- Flash attention: 48KB LDS (K dbuf + V single), 3 waves/SIMD --
// Per tile: bar1; issue V(t)+K(t+1); vmcnt(8); bar2; QK^T+softmax;
//           vmcnt(4); bar3; PV.   Counted waits keep prefetch in flight (T4).
// XCD grouping BY KV-PANEL: lid&7 = b*4+kvh -> panel + its Q L2-resident.
__global__ __launch_bounds__(256, 3)
void attn_kernel(const bf16_t* __restrict__ Qr,
                 const bf16_t* __restrict__ Kf,
                 const bf16_t* __restrict__ Vf,
                 float* __restrict__ out,
                 float* __restrict__ Opart,
                 float2* __restrict__ mlpart,
                 int split, int upb) {
  __shared__ bf16_t Kb[2][KVB * HD];   // 16 KB x2, fragment order
  __shared__ bf16_t Vb[HD * KVB];      // 16 KB single buffer, fragment order

  const int w    = threadIdx.x >> 6;
  const int lane = threadIdx.x & 63;
  const int r0   = lane & 31;
  const int hi   = lane >> 5;

  // decode flat id -> (panel, head, unit); panel pinned to XCD via lid&7
  const int lid = (int)blockIdx.x;
  const int p   = lid & 7;            // kv panel = b*4 + kvh
  const int qq  = lid >> 3;
  const int j   = qq & 3;             // head within panel
  const int k   = qq >> 2;            // unit index 0..upb-1
  const int b   = p >> 2;
  const int kvh = p & 3;
  const int h   = kvh * 4 + j;
  const int bh  = b * 16 + h;
  const int u   = split ? kOrder24[k] : (15 - k);
  int qt, t0, t1;
  if (!split || u < 8) {
    qt = u; t0 = 0; t1 = 2 * qt + 2;               // all kv tiles for this q-tile
  } else {
    int v = u - 8;
    qt = 8 + (v >> 1);
    int T = 2 * qt + 2, mid = qt + 1;              // two equal chunks of qt+1
    if (v & 1) { t0 = mid; t1 = T; } else { t0 = 0; t1 = mid; }
  }
  const bool full = (t0 == 0) && (t1 == 2 * qt + 2);
  const int qw0  = qt * QBB + w * QBW;
  const int qrow = qw0 + r0;
  const int qmax = qw0 + 31;

  const bf16_t* Qbase = Qr + (size_t)(b * HQ  + h  ) * S_LEN * HD;
  const bf16_t* Kbase = Kf + (size_t)(b * HKV + kvh) * 32 * (KVB * HD);
  const bf16_t* Vbase = Vf + (size_t)(b * HKV + kvh) * 32 * (HD * KVB);

  // linear staging offsets: wave w covers chunks [w*256, w*256+256)
  const int soff = (w * 256 + lane) * 8;           // + i*512 per iter

  // Q fragments (B-operand of swapped QK^T): lane holds Q[qrow][kk*16+hi*8 ..+8)
  bf16x8 qf[8];
  #pragma unroll
  for (int kk = 0; kk < 8; ++kk)
    qf[kk] = *reinterpret_cast<const bf16x8*>(Qbase + (size_t)qrow * HD + kk * 16 + hi * 8);

  f32x16 accO[4];
  #pragma unroll
  for (int dt = 0; dt < 4; ++dt)
    #pragma unroll
    for (int e = 0; e < 16; ++e) accO[dt][e] = 0.f;
  float m = -3.0e38f, l = 0.f;

  // prologue: stage K(t0) into Kb[0] (DMA, no VGPRs); no drain here
  {
    const bf16_t* kg = Kbase + (size_t)t0 * (KVB * HD);
    #pragma unroll
    for (int i = 0; i < 4; ++i)
      gload_lds16(kg + soff + i * 512, &Kb[0][soff + i * 512]);
  }

  for (int t = t0; t < t1; ++t) {
    const int pb = (t - t0) & 1;
    // bar1: all waves done reading Kb[pb^1] (tile t-1) and Vb (tile t-1's PV)
    __builtin_amdgcn_s_barrier();
    {
      const bf16_t* vg = Vbase + (size_t)t * (HD * KVB);
      #pragma unroll
      for (int i = 0; i < 4; ++i)                   // V(t) first (older)
        gload_lds16(vg + soff + i * 512, &Vb[soff + i * 512]);
      const int tn = (t + 1 < t1) ? t + 1 : t;      // last iter: dummy re-stage
      const bf16_t* kg = Kbase + (size_t)tn * (KVB * HD);
      #pragma unroll
      for (int i = 0; i < 4; ++i)                   // then K(t+1)
        gload_lds16(kg + soff + i * 512, &Kb[pb ^ 1][soff + i * 512]);
    }
    // wait K(t) (the 8 newer = V(t)+K(t+1) stay in flight)
    asm volatile("s_waitcnt vmcnt(8)" ::: "memory");
    __builtin_amdgcn_sched_barrier(0);
    __builtin_amdgcn_s_barrier();      // bar2: tile-t K visible block-wide
    __builtin_amdgcn_sched_barrier(0);

    const int kv0 = t * KVB;
    const bool active = (kv0 <= qmax);
    float p2[32];
    u32x4 pw[4];
    if (active) {
      // ---- S^T = K Q^T : fragment reads are base + kk*1024(+512) + lane*8
      const bf16_t* kb = &Kb[pb][0];
      f32x16 st0, st1;
      #pragma unroll
      for (int e = 0; e < 16; ++e) { st0[e] = 0.f; st1[e] = 0.f; }
      __builtin_amdgcn_s_setprio(1);
      #pragma unroll
      for (int kk = 0; kk < 8; ++kk) {
        bf16x8 k0 = *reinterpret_cast<const bf16x8*>(kb + kk * 1024 + lane * 8);
        bf16x8 k1 = *reinterpret_cast<const bf16x8*>(kb + kk * 1024 + 512 + lane * 8);
        st0 = __builtin_amdgcn_mfma_f32_32x32x16_bf16(k0, qf[kk], st0, 0, 0, 0);
        st1 = __builtin_amdgcn_mfma_f32_32x32x16_bf16(k1, qf[kk], st1, 0, 0, 0);
      }
      __builtin_amdgcn_s_setprio(0);

      // ---- in-register softmax (lane owns q-row r0; partner lane other 16)
      const bool need_mask = (kv0 + 63 > qw0);
      #pragma unroll
      for (int jj = 0; jj < 2; ++jj)
        #pragma unroll
        for (int e = 0; e < 16; ++e) {
          float s = jj ? st1[e] : st0[e];
          if (need_mask) {
            int kv = kv0 + jj * 32 + (e & 3) + 8 * (e >> 2) + 4 * hi;
            s = (kv > qrow) ? -3.0e38f : s;
          }
          p2[jj * 16 + e] = s;
        }
      float mt[16];
      #pragma unroll
      for (int e = 0; e < 16; ++e) mt[e] = fmaxf(p2[e], p2[e + 16]);
      #pragma unroll
      for (int e = 0; e < 8; ++e) mt[e] = fmaxf(mt[e], mt[e + 8]);
      #pragma unroll
      for (int e = 0; e < 4; ++e) mt[e] = fmaxf(mt[e], mt[e + 4]);
      float lmx = fmaxf(fmaxf(mt[0], mt[1]), fmaxf(mt[2], mt[3]));
      float cmx = fmaxf(lmx, __shfl_xor(lmx, 32, 64));
      if (!__all(cmx <= m + 8.0f)) {        // T13 defer-max
        float mnew = fmaxf(m, cmx);
        float resc = __builtin_amdgcn_exp2f(m - mnew);
        m = mnew;
        l *= resc;
        #pragma unroll
        for (int dt = 0; dt < 4; ++dt)
          #pragma unroll
          for (int e = 0; e < 16; ++e) accO[dt][e] *= resc;
      }
      #pragma unroll
      for (int e = 0; e < 32; ++e) p2[e] = __builtin_amdgcn_exp2f(p2[e] - m);
      float sv[16];
      #pragma unroll
      for (int e = 0; e < 16; ++e) sv[e] = p2[e] + p2[e + 16];
      #pragma unroll
      for (int e = 0; e < 8; ++e) sv[e] += sv[e + 8];
      #pragma unroll
      for (int e = 0; e < 4; ++e) sv[e] += sv[e + 4];
      float lsum = (sv[0] + sv[1]) + (sv[2] + sv[3]);
      l += lsum + __shfl_xor(lsum, 32, 64);

      // ---- P -> bf16 B-fragments (partner exchange via shfl_xor)
      #pragma unroll
      for (int jj = 0; jj < 2; ++jj) {
        const int o = jj * 16;
        {
          uint32_t A = pack2(p2[o + 0], p2[o + 1]);
          uint32_t C = pack2(p2[o + 2], p2[o + 3]);
          uint32_t B = pack2(p2[o + 4], p2[o + 5]);
          uint32_t D = pack2(p2[o + 6], p2[o + 7]);
          uint32_t At = __shfl_xor(A, 32, 64), Ct = __shfl_xor(C, 32, 64);
          uint32_t Bt = __shfl_xor(B, 32, 64), Dt = __shfl_xor(D, 32, 64);
          pw[2 * jj] = hi ? (u32x4){Bt, Dt, B, D} : (u32x4){A, C, At, Ct};
        }
        {
          uint32_t A = pack2(p2[o + 8],  p2[o + 9]);
          uint32_t C = pack2(p2[o + 10], p2[o + 11]);
          uint32_t B = pack2(p2[o + 12], p2[o + 13]);
          uint32_t D = pack2(p2[o + 14], p2[o + 15]);
          uint32_t At = __shfl_xor(A, 32, 64), Ct = __shfl_xor(C, 32, 64);
          uint32_t Bt = __shfl_xor(B, 32, 64), Dt = __shfl_xor(D, 32, 64);
          pw[2 * jj + 1] = hi ? (u32x4){Bt, Dt, B, D} : (u32x4){A, C, At, Ct};
        }
      }
    }

    // wait V(t) (K(t+1) stays in flight), then block-wide visibility
    asm volatile("s_waitcnt vmcnt(4)" ::: "memory");
    __builtin_amdgcn_sched_barrier(0);
    __builtin_amdgcn_s_barrier();      // bar3: tile-t V visible block-wide
    __builtin_amdgcn_sched_barrier(0);

    if (active) {
      // ---- O^T += V^T P^T : fragment reads base + kk*2048 + dt*512 + lane*8
      const bf16_t* vb = &Vb[0];
      __builtin_amdgcn_s_setprio(1);
      #pragma unroll
      for (int kk = 0; kk < 4; ++kk) {
        bf16x8 pf = __builtin_bit_cast(bf16x8, pw[kk]);
        #pragma unroll
        for (int dt = 0; dt < 4; ++dt) {
          bf16x8 vf = *reinterpret_cast<const bf16x8*>(vb + kk * 2048 + dt * 512 + lane * 8);
          accO[dt] = __builtin_amdgcn_mfma_f32_32x32x16_bf16(vf, pf, accO[dt], 0, 0, 0);
        }
      }
      __builtin_amdgcn_s_setprio(0);
    }
  }

  if (full) {
    // ---- direct output
    const float inv = 1.0f / l;
    float* orow = out + ((size_t)(b * S_LEN + qrow) * (HQ * HD)) + h * HD + hi * 4;
    #pragma unroll
    for (int dt = 0; dt < 4; ++dt)
      #pragma unroll
      for (int rg = 0; rg < 4; ++rg) {
        f32x4 v4 = { accO[dt][4 * rg + 0] * inv, accO[dt][4 * rg + 1] * inv,
                     accO[dt][4 * rg + 2] * inv, accO[dt][4 * rg + 3] * inv };
        *reinterpret_cast<f32x4*>(orow + dt * 32 + rg * 8) = v4;
      }
  } else {
    // ---- partial output (unnormalized, with local m,l)
    const int c    = (t0 != 0) ? 1 : 0;
    const int pidx = ((bh << 3) + (qt - 8)) * 2 + c;
    float* Op = Opart + (size_t)pidx * (QBB * HD) + (size_t)(w * QBW + r0) * HD + hi * 4;
    #pragma unroll
    for (int dt = 0; dt < 4; ++dt)
      #pragma unroll
      for (int rg = 0; rg < 4; ++rg) {
        f32x4 v4 = { accO[dt][4 * rg + 0], accO[dt][4 * rg + 1],
                     accO[dt][4 * rg + 2], accO[dt][4 * rg + 3] };
        *reinterpret_cast<f32x4*>(Op + dt * 32 + rg * 8) = v4;
      }
    if (!hi) mlpart[(size_t)pidx * QBB + w * QBW + r0] = make_float2(m, l);
  }
}

// ---------------- combine two kv-chunk partials per split q-tile ---------------
__global__ void combine_kernel(const float* __restrict__ Opart,
                               const float2* __restrict__ mlpart,
                               float* __restrict__ out) {
  const int j  = blockIdx.x;          // bh*8 + (qt-8), 0..255
  const int bh = j >> 3;
  const int qt = 8 + (j & 7);
  const int b  = bh >> 4;
  const int h  = bh & 15;
  const int r  = threadIdx.x >> 1;            // 0..127
  const int d0 = (threadIdx.x & 1) * 64;
  const size_t p0 = (size_t)(j * 2)     * (QBB * HD) + (size_t)r * HD + d0;
  const size_t p1 = (size_t)(j * 2 + 1) * (QBB * HD) + (size_t)r * HD + d0;
  const float2 ml0 = mlpart[(size_t)(j * 2)     * QBB + r];
  const float2 ml1 = mlpart[(size_t)(j * 2 + 1) * QBB + r];
  const float M  = fmaxf(ml0.x, ml1.x);
  float a0 = exp2f(ml0.x - M), a1 = exp2f(ml1.x - M);
  const float inv = 1.0f / (a0 * ml0.y + a1 * ml1.y);
  a0 *= inv; a1 *= inv;
  const int qrow = qt * QBB + r;
  float* orow = out + ((size_t)(b * S_LEN + qrow) * (HQ * HD)) + h * HD + d0;
  #pragma unroll
  for (int i = 0; i < 16; ++i) {
    f32x4 o0 = *reinterpret_cast<const f32x4*>(Opart + p0 + i * 4);
    f32x4 o1 = *reinterpret_cast<const f32x4*>(Opart + p1 + i * 4);
    f32x4 res = { a0 * o0[0] + a1 * o1[0], a0 * o0[1] + a1 * o1[1],
                  a0 * o0[2] + a1 * o1[2], a0 * o0[3] + a1 * o1[3] };
    *reinterpret_cast<f32x4*>(orow + i * 4) = res;
  }
}

extern "C" void kernel_launch(void* const* d_in, const int* in_sizes, int n_in,
                              void* d_out, int out_size, void* d_ws, size_t ws_size,
                              hipStream_t stream) {
  const float* xq = (const float*)d_in[0];
  const float* xk = (const float*)d_in[1];
  const float* xv = (const float*)d_in[2];
  float* out = (float*)d_out;

  char* ws = (char*)d_ws;
  size_t off = 0;
  bf16_t* Qr = (bf16_t*)(ws + off); off += (size_t)NB * HQ  * S_LEN * HD * sizeof(bf16_t);
  bf16_t* Kf = (bf16_t*)(ws + off); off += (size_t)NB * HKV * S_LEN * HD * sizeof(bf16_t);
  bf16_t* Vf = (bf16_t*)(ws + off); off += (size_t)NB * HKV * S_LEN * HD * sizeof(bf16_t);
  float*  Opart  = (float*)(ws + off);  off += (size_t)512 * QBB * HD * sizeof(float);
  float2* mlpart = (float2*)(ws + off); off += (size_t)512 * QBB * sizeof(float2);
  const int split = (ws_size >= off) ? 1 : 0;   // split-K needs the partial buffers
  const int upb   = split ? 24 : 16;            // units per (b,h)

  const int nrow = NB * S_LEN * (HQ + HKV);
  preproc_kernel<<<NVBLK + nrow / 4, 256, 0, stream>>>(xq, xk, xv, Qr, Kf, Vf);

  attn_kernel<<<32 * upb, 256, 0, stream>>>(Qr, Kf, Vf, out, Opart, mlpart,
                                            split, upb);
  if (split)
    combine_kernel<<<256, 256, 0, stream>>>(Opart, mlpart, out);
}

// Round 17
// 91.854 us; speedup vs baseline: 2.4224x; 1.0282x over previous
//
#include <hip/hip_runtime.h>
#include <hip/hip_bf16.h>
#include <stdint.h>

#define S_LEN 2048
#define NB    2
#define HQ    16
#define HKV   4
#define HD    128
#define KVB   64   // kv rows per staged tile
#define QBW   32   // q rows per wave
#define QBB   128  // q rows per block (4 waves)

typedef __bf16 bf16_t;
typedef __attribute__((ext_vector_type(4)))  __bf16 bf16x4;
typedef __attribute__((ext_vector_type(8)))  __bf16 bf16x8;
typedef __attribute__((ext_vector_type(4)))  float  f32x4;
typedef __attribute__((ext_vector_type(16))) float  f32x16;
typedef __attribute__((ext_vector_type(4)))  unsigned int u32x4;

#define NVBLK 512          // v-preproc blocks (placed first in merged grid)

// heavy-first order of the 24 units per bh.
__constant__ int kOrder24[24] = {7,22,23,20,21, 6,18,19,16,17, 5,14,15,12,13,
                                 4,10,11,8,9, 3, 2, 1, 0};

__device__ __forceinline__ void gload_lds16(const bf16_t* g, bf16_t* l) {
  __builtin_amdgcn_global_load_lds(
      (const __attribute__((address_space(1))) unsigned int*)g,
      (__attribute__((address_space(3))) unsigned int*)l, 16, 0, 0);
}
__device__ __forceinline__ uint32_t pack2(float lo, float hi) {
  uint32_t a = (uint32_t)__builtin_bit_cast(unsigned short, (bf16_t)lo);
  uint32_t b = (uint32_t)__builtin_bit_cast(unsigned short, (bf16_t)hi);
  return a | (b << 16);
}
// v_permlane32_swap_b32 X, Y:  X' = {X[0:31], Y[0:31]},  Y' = {X[32:63], Y[32:63]}
__device__ __forceinline__ void plswap(uint32_t& x, uint32_t& y) {
  asm volatile("v_permlane32_swap_b32 %0, %1" : "+v"(x), "+v"(y));
}

// ---------------- merged preproc: v-transpose blocks first, then q/k blocks ----
__global__ void preproc_kernel(const float* __restrict__ xq,
                               const float* __restrict__ xk,
                               const float* __restrict__ xv,
                               bf16_t* __restrict__ Qr,
                               bf16_t* __restrict__ Kf,
                               bf16_t* __restrict__ Vf) {
  __shared__ bf16_t tile[HD][34];    // v-path only; +2 pad kills write conflicts
  if (blockIdx.x < NVBLK) {
    // ---------- V path: coalesced read -> LDS transpose -> fragment-order write
    const int bid = blockIdx.x;
    const int bh  = bid >> 6;          // b*HKV + h
    const int r6  = bid & 63;
    const int sc  = r6 >> 1;           // 64-row s chunk (= tile t)
    const int j   = r6 & 1;            // which 32-kv half
    const int b = bh >> 2, hh = bh & 3;
    const int d  = threadIdx.x & 127;
    const int s2 = threadIdx.x >> 7;   // 0..1
    const float* src = xv + (size_t)b * S_LEN * (HKV * HD) + hh * HD;
    #pragma unroll 4
    for (int it = 0; it < 16; ++it) {
      int sl = it * 2 + s2;            // 0..31 (local)
      int s  = sc * 64 + j * 32 + sl;
      tile[d][sl] = (bf16_t)src[(size_t)s * (HKV * HD) + d];
    }
    __syncthreads();
    bf16_t* dstb = Vf + ((size_t)bh * 32 + sc) * (HD * KVB);
    const int dd   = threadIdx.x >> 1;           // d-row 0..127
    const int dt   = dd >> 5, r0v = dd & 31;
    #pragma unroll
    for (int i = 0; i < 2; ++i) {
      const int cl = (threadIdx.x & 1) * 2 + i;  // local chunk 0..3
      const int c  = j * 4 + cl;                 // global kv chunk
      const int n  = (c >> 1) * 256 + dt * 64 + (c & 1) * 32 + r0v;
      *reinterpret_cast<bf16x8*>(dstb + n * 8) =
          *reinterpret_cast<const bf16x8*>(&tile[dd][cl * 8]);
    }
    return;
  }
  // ---------- Q/K path: L2-norm + RoPE (fast trig) + bf16
  int wid  = ((blockIdx.x - NVBLK) * blockDim.x + threadIdx.x) >> 6;
  int lane = threadIdx.x & 63;
  const int per_bs = HQ + HKV;
  int b   = wid / (S_LEN * per_bs);
  int rem = wid - b * (S_LEN * per_bs);
  int s   = rem / per_bs;
  int hh  = rem - s * per_bs;
  const float* src;
  float scale;
  if (hh < HQ) {
    src = xq + ((size_t)(b * S_LEN + s) * (HQ * HD)) + hh * HD;
    scale = 0.08838834764831845f * 1.4426950408889634f;  // (1/sqrt128)*log2e
  } else {
    src = xk + ((size_t)(b * S_LEN + s) * (HKV * HD)) + (hh - HQ) * HD;
    scale = 1.0f;
  }
  float x1 = src[lane];
  float x2 = src[64 + lane];
  float ss = x1 * x1 + x2 * x2;
  #pragma unroll
  for (int mm = 1; mm < 64; mm <<= 1) ss += __shfl_xor(ss, mm, 64);
  float rinv = scale / fmaxf(sqrtf(ss), 1e-6f);
  float inv = exp2f(-(float)lane * 0.20762050593046938f);
  float ang = (float)s * inv;
  float cs = __cosf(ang), sn = __sinf(ang);   // v_cos/v_sin fast path
  float q1 = x1 * rinv, q2 = x2 * rinv;
  bf16_t y1 = (bf16_t)(q1 * cs + q2 * sn);
  bf16_t y2 = (bf16_t)(q2 * cs - q1 * sn);
  if (hh < HQ) {
    bf16_t* dst = Qr + (((size_t)(b * HQ + hh) * S_LEN + s) * HD);
    dst[lane]      = y1;
    dst[64 + lane] = y2;
  } else {
    bf16_t* dst = Kf + ((size_t)((b * HKV + (hh - HQ)) * 32 + (s >> 6))) * (KVB * HD);
    const int sl = s & 63, half = sl >> 5, r0k = sl & 31;
    const int kk = lane >> 4, hi = (lane >> 3) & 1, pos = lane & 7;
    const int a1 = (kk * 128 + half * 64 + hi * 32 + r0k) * 8 + pos;
    dst[a1]        = y1;   // d = lane       (kk 0..3)
    dst[a1 + 4096] = y2;   // d = 64 + lane  (kk 4..7)
  }
}

// ---------------- Flash attention: 48KB LDS (K dbuf + V single), 3 waves/SIMD --
// Per tile: bar1; issue V(t)+K(t+1); vmcnt(8); bar2; QK^T+softmax;
//           vmcnt(4); bar3; PV.   Counted waits keep prefetch in flight (T4).
// XCD grouping BY KV-PANEL: lid&7 = b*4+kvh -> panel + its Q L2-resident.
// Partials are written NORMALIZED (x 1/l) as bf16 -> half combine traffic.
__global__ __launch_bounds__(256, 3)
void attn_kernel(const bf16_t* __restrict__ Qr,
                 const bf16_t* __restrict__ Kf,
                 const bf16_t* __restrict__ Vf,
                 float* __restrict__ out,
                 bf16_t* __restrict__ Opart,
                 float2* __restrict__ mlpart,
                 int split, int upb) {
  __shared__ bf16_t Kb[2][KVB * HD];   // 16 KB x2, fragment order
  __shared__ bf16_t Vb[HD * KVB];      // 16 KB single buffer, fragment order

  const int w    = threadIdx.x >> 6;
  const int lane = threadIdx.x & 63;
  const int r0   = lane & 31;
  const int hi   = lane >> 5;

  // decode flat id -> (panel, head, unit); panel pinned to XCD via lid&7
  const int lid = (int)blockIdx.x;
  const int p   = lid & 7;            // kv panel = b*4 + kvh
  const int qq  = lid >> 3;
  const int j   = qq & 3;             // head within panel
  const int k   = qq >> 2;            // unit index 0..upb-1
  const int b   = p >> 2;
  const int kvh = p & 3;
  const int h   = kvh * 4 + j;
  const int bh  = b * 16 + h;
  const int u   = split ? kOrder24[k] : (15 - k);
  int qt, t0, t1;
  if (!split || u < 8) {
    qt = u; t0 = 0; t1 = 2 * qt + 2;               // all kv tiles for this q-tile
  } else {
    int v = u - 8;
    qt = 8 + (v >> 1);
    int T = 2 * qt + 2, mid = qt + 1;              // two equal chunks of qt+1
    if (v & 1) { t0 = mid; t1 = T; } else { t0 = 0; t1 = mid; }
  }
  const bool full = (t0 == 0) && (t1 == 2 * qt + 2);
  const int qw0  = qt * QBB + w * QBW;
  const int qrow = qw0 + r0;
  const int qmax = qw0 + 31;

  const bf16_t* Qbase = Qr + (size_t)(b * HQ  + h  ) * S_LEN * HD;
  const bf16_t* Kbase = Kf + (size_t)(b * HKV + kvh) * 32 * (KVB * HD);
  const bf16_t* Vbase = Vf + (size_t)(b * HKV + kvh) * 32 * (HD * KVB);

  // linear staging offsets: wave w covers chunks [w*256, w*256+256)
  const int soff = (w * 256 + lane) * 8;           // + i*512 per iter

  // Q fragments (B-operand of swapped QK^T): lane holds Q[qrow][kk*16+hi*8 ..+8)
  bf16x8 qf[8];
  #pragma unroll
  for (int kk = 0; kk < 8; ++kk)
    qf[kk] = *reinterpret_cast<const bf16x8*>(Qbase + (size_t)qrow * HD + kk * 16 + hi * 8);

  f32x16 accO[4];
  #pragma unroll
  for (int dt = 0; dt < 4; ++dt)
    #pragma unroll
    for (int e = 0; e < 16; ++e) accO[dt][e] = 0.f;
  float m = -3.0e38f, l = 0.f;

  // prologue: stage K(t0) into Kb[0] (DMA, no VGPRs); no drain here
  {
    const bf16_t* kg = Kbase + (size_t)t0 * (KVB * HD);
    #pragma unroll
    for (int i = 0; i < 4; ++i)
      gload_lds16(kg + soff + i * 512, &Kb[0][soff + i * 512]);
  }

  for (int t = t0; t < t1; ++t) {
    const int pb = (t - t0) & 1;
    // bar1: all waves done reading Kb[pb^1] (tile t-1) and Vb (tile t-1's PV)
    __builtin_amdgcn_s_barrier();
    {
      const bf16_t* vg = Vbase + (size_t)t * (HD * KVB);
      #pragma unroll
      for (int i = 0; i < 4; ++i)                   // V(t) first (older)
        gload_lds16(vg + soff + i * 512, &Vb[soff + i * 512]);
      const int tn = (t + 1 < t1) ? t + 1 : t;      // last iter: dummy re-stage
      const bf16_t* kg = Kbase + (size_t)tn * (KVB * HD);
      #pragma unroll
      for (int i = 0; i < 4; ++i)                   // then K(t+1)
        gload_lds16(kg + soff + i * 512, &Kb[pb ^ 1][soff + i * 512]);
    }
    // wait K(t) (the 8 newer = V(t)+K(t+1) stay in flight)
    asm volatile("s_waitcnt vmcnt(8)" ::: "memory");
    __builtin_amdgcn_sched_barrier(0);
    __builtin_amdgcn_s_barrier();      // bar2: tile-t K visible block-wide
    __builtin_amdgcn_sched_barrier(0);

    const int kv0 = t * KVB;
    const bool active = (kv0 <= qmax);
    float p2[32];
    u32x4 pw[4];
    if (active) {
      // ---- S^T = K Q^T : fragment reads are base + kk*1024(+512) + lane*8
      const bf16_t* kb = &Kb[pb][0];
      f32x16 st0, st1;
      #pragma unroll
      for (int e = 0; e < 16; ++e) { st0[e] = 0.f; st1[e] = 0.f; }
      __builtin_amdgcn_s_setprio(1);
      #pragma unroll
      for (int kk = 0; kk < 8; ++kk) {
        bf16x8 k0 = *reinterpret_cast<const bf16x8*>(kb + kk * 1024 + lane * 8);
        bf16x8 k1 = *reinterpret_cast<const bf16x8*>(kb + kk * 1024 + 512 + lane * 8);
        st0 = __builtin_amdgcn_mfma_f32_32x32x16_bf16(k0, qf[kk], st0, 0, 0, 0);
        st1 = __builtin_amdgcn_mfma_f32_32x32x16_bf16(k1, qf[kk], st1, 0, 0, 0);
      }
      __builtin_amdgcn_s_setprio(0);

      // ---- in-register softmax (lane owns q-row r0; partner lane other 16)
      const bool need_mask = (kv0 + 63 > qw0);
      #pragma unroll
      for (int jj = 0; jj < 2; ++jj)
        #pragma unroll
        for (int e = 0; e < 16; ++e) {
          float s = jj ? st1[e] : st0[e];
          if (need_mask) {
            int kv = kv0 + jj * 32 + (e & 3) + 8 * (e >> 2) + 4 * hi;
            s = (kv > qrow) ? -3.0e38f : s;
          }
          p2[jj * 16 + e] = s;
        }
      float mt[16];
      #pragma unroll
      for (int e = 0; e < 16; ++e) mt[e] = fmaxf(p2[e], p2[e + 16]);
      #pragma unroll
      for (int e = 0; e < 8; ++e) mt[e] = fmaxf(mt[e], mt[e + 8]);
      #pragma unroll
      for (int e = 0; e < 4; ++e) mt[e] = fmaxf(mt[e], mt[e + 4]);
      float lmx = fmaxf(fmaxf(mt[0], mt[1]), fmaxf(mt[2], mt[3]));
      float cmx = fmaxf(lmx, __shfl_xor(lmx, 32, 64));
      if (!__all(cmx <= m + 8.0f)) {        // T13 defer-max
        float mnew = fmaxf(m, cmx);
        float resc = __builtin_amdgcn_exp2f(m - mnew);
        m = mnew;
        l *= resc;
        #pragma unroll
        for (int dt = 0; dt < 4; ++dt)
          #pragma unroll
          for (int e = 0; e < 16; ++e) accO[dt][e] *= resc;
      }
      #pragma unroll
      for (int e = 0; e < 32; ++e) p2[e] = __builtin_amdgcn_exp2f(p2[e] - m);
      float sv[16];
      #pragma unroll
      for (int e = 0; e < 16; ++e) sv[e] = p2[e] + p2[e + 16];
      #pragma unroll
      for (int e = 0; e < 8; ++e) sv[e] += sv[e + 8];
      #pragma unroll
      for (int e = 0; e < 4; ++e) sv[e] += sv[e + 4];
      float lsum = (sv[0] + sv[1]) + (sv[2] + sv[3]);
      l += lsum + __shfl_xor(lsum, 32, 64);

      // ---- P -> bf16 B-fragments via permlane32_swap (T12, select-free)
      #pragma unroll
      for (int jj = 0; jj < 2; ++jj) {
        const int o = jj * 16;
        {
          uint32_t A = pack2(p2[o + 0], p2[o + 1]);
          uint32_t C = pack2(p2[o + 2], p2[o + 3]);
          uint32_t B = pack2(p2[o + 4], p2[o + 5]);
          uint32_t D = pack2(p2[o + 6], p2[o + 7]);
          plswap(A, B);   // A={A_lo,B_lo}=word0, B={A_hi,B_hi}=word2
          plswap(C, D);   // C=word1, D=word3
          pw[2 * jj] = (u32x4){A, C, B, D};
        }
        {
          uint32_t A = pack2(p2[o + 8],  p2[o + 9]);
          uint32_t C = pack2(p2[o + 10], p2[o + 11]);
          uint32_t B = pack2(p2[o + 12], p2[o + 13]);
          uint32_t D = pack2(p2[o + 14], p2[o + 15]);
          plswap(A, B);
          plswap(C, D);
          pw[2 * jj + 1] = (u32x4){A, C, B, D};
        }
      }
    }

    // wait V(t) (K(t+1) stays in flight), then block-wide visibility
    asm volatile("s_waitcnt vmcnt(4)" ::: "memory");
    __builtin_amdgcn_sched_barrier(0);
    __builtin_amdgcn_s_barrier();      // bar3: tile-t V visible block-wide
    __builtin_amdgcn_sched_barrier(0);

    if (active) {
      // ---- O^T += V^T P^T : fragment reads base + kk*2048 + dt*512 + lane*8
      const bf16_t* vb = &Vb[0];
      __builtin_amdgcn_s_setprio(1);
      #pragma unroll
      for (int kk = 0; kk < 4; ++kk) {
        bf16x8 pf = __builtin_bit_cast(bf16x8, pw[kk]);
        #pragma unroll
        for (int dt = 0; dt < 4; ++dt) {
          bf16x8 vf = *reinterpret_cast<const bf16x8*>(vb + kk * 2048 + dt * 512 + lane * 8);
          accO[dt] = __builtin_amdgcn_mfma_f32_32x32x16_bf16(vf, pf, accO[dt], 0, 0, 0);
        }
      }
      __builtin_amdgcn_s_setprio(0);
    }
  }

  const float inv = 1.0f / l;
  if (full) {
    // ---- direct output
    float* orow = out + ((size_t)(b * S_LEN + qrow) * (HQ * HD)) + h * HD + hi * 4;
    #pragma unroll
    for (int dt = 0; dt < 4; ++dt)
      #pragma unroll
      for (int rg = 0; rg < 4; ++rg) {
        f32x4 v4 = { accO[dt][4 * rg + 0] * inv, accO[dt][4 * rg + 1] * inv,
                     accO[dt][4 * rg + 2] * inv, accO[dt][4 * rg + 3] * inv };
        *reinterpret_cast<f32x4*>(orow + dt * 32 + rg * 8) = v4;
      }
  } else {
    // ---- partial output: NORMALIZED, bf16 (O(1)-bounded -> bf16-safe)
    const int c    = (t0 != 0) ? 1 : 0;
    const int pidx = ((bh << 3) + (qt - 8)) * 2 + c;
    bf16_t* Op = Opart + (size_t)pidx * (QBB * HD) + (size_t)(w * QBW + r0) * HD + hi * 4;
    #pragma unroll
    for (int dt = 0; dt < 4; ++dt)
      #pragma unroll
      for (int rg = 0; rg < 4; ++rg) {
        bf16x4 v4 = { (bf16_t)(accO[dt][4 * rg + 0] * inv),
                      (bf16_t)(accO[dt][4 * rg + 1] * inv),
                      (bf16_t)(accO[dt][4 * rg + 2] * inv),
                      (bf16_t)(accO[dt][4 * rg + 3] * inv) };
        *reinterpret_cast<bf16x4*>(Op + dt * 32 + rg * 8) = v4;
      }
    if (!hi) mlpart[(size_t)pidx * QBB + w * QBW + r0] = make_float2(m, l);
  }
}

// ---------------- combine two kv-chunk partials per split q-tile ---------------
// Partials are normalized: out = w0*O0^ + w1*O1^, w_i = l_i*2^(m_i-M) / sum.
__global__ void combine_kernel(const bf16_t* __restrict__ Opart,
                               const float2* __restrict__ mlpart,
                               float* __restrict__ out) {
  const int j  = blockIdx.x;          // bh*8 + (qt-8), 0..255
  const int bh = j >> 3;
  const int qt = 8 + (j & 7);
  const int b  = bh >> 4;
  const int h  = bh & 15;
  const int r  = threadIdx.x >> 1;            // 0..127
  const int d0 = (threadIdx.x & 1) * 64;
  const size_t pj0 = (size_t)(j * 2)     * (QBB * HD) + (size_t)r * HD + d0;
  const size_t pj1 = (size_t)(j * 2 + 1) * (QBB * HD) + (size_t)r * HD + d0;
  const float2 ml0 = mlpart[(size_t)(j * 2)     * QBB + r];
  const float2 ml1 = mlpart[(size_t)(j * 2 + 1) * QBB + r];
  const float M  = fmaxf(ml0.x, ml1.x);
  float b0 = exp2f(ml0.x - M) * ml0.y;
  float b1 = exp2f(ml1.x - M) * ml1.y;
  const float inv = 1.0f / (b0 + b1);
  b0 *= inv; b1 *= inv;
  const int qrow = qt * QBB + r;
  float* orow = out + ((size_t)(b * S_LEN + qrow) * (HQ * HD)) + h * HD + d0;
  #pragma unroll
  for (int i = 0; i < 8; ++i) {
    bf16x8 o0 = *reinterpret_cast<const bf16x8*>(Opart + pj0 + i * 8);
    bf16x8 o1 = *reinterpret_cast<const bf16x8*>(Opart + pj1 + i * 8);
    f32x4 lo = { b0 * (float)o0[0] + b1 * (float)o1[0],
                 b0 * (float)o0[1] + b1 * (float)o1[1],
                 b0 * (float)o0[2] + b1 * (float)o1[2],
                 b0 * (float)o0[3] + b1 * (float)o1[3] };
    f32x4 hi4 = { b0 * (float)o0[4] + b1 * (float)o1[4],
                  b0 * (float)o0[5] + b1 * (float)o1[5],
                  b0 * (float)o0[6] + b1 * (float)o1[6],
                  b0 * (float)o0[7] + b1 * (float)o1[7] };
    *reinterpret_cast<f32x4*>(orow + i * 8)     = lo;
    *reinterpret_cast<f32x4*>(orow + i * 8 + 4) = hi4;
  }
}

extern "C" void kernel_launch(void* const* d_in, const int* in_sizes, int n_in,
                              void* d_out, int out_size, void* d_ws, size_t ws_size,
                              hipStream_t stream) {
  const float* xq = (const float*)d_in[0];
  const float* xk = (const float*)d_in[1];
  const float* xv = (const float*)d_in[2];
  float* out = (float*)d_out;

  char* ws = (char*)d_ws;
  size_t off = 0;
  bf16_t* Qr = (bf16_t*)(ws + off); off += (size_t)NB * HQ  * S_LEN * HD * sizeof(bf16_t);
  bf16_t* Kf = (bf16_t*)(ws + off); off += (size_t)NB * HKV * S_LEN * HD * sizeof(bf16_t);
  bf16_t* Vf = (bf16_t*)(ws + off); off += (size_t)NB * HKV * S_LEN * HD * sizeof(bf16_t);
  bf16_t* Opart  = (bf16_t*)(ws + off); off += (size_t)512 * QBB * HD * sizeof(bf16_t);
  float2* mlpart = (float2*)(ws + off); off += (size_t)512 * QBB * sizeof(float2);
  const int split = (ws_size >= off) ? 1 : 0;   // split-K needs the partial buffers
  const int upb   = split ? 24 : 16;            // units per (b,h)

  const int nrow = NB * S_LEN * (HQ + HKV);
  preproc_kernel<<<NVBLK + nrow / 4, 256, 0, stream>>>(xq, xk, xv, Qr, Kf, Vf);

  attn_kernel<<<32 * upb, 256, 0, stream>>>(Qr, Kf, Vf, out, Opart, mlpart,
                                            split, upb);
  if (split)
    combine_kernel<<<256, 256, 0, stream>>>(Opart, mlpart, out);
}